// Round 1
// baseline (4541.125 us; speedup 1.0000x reference)
//
#include <hip/hip_runtime.h>

// RPN head, 5 FPN levels. Pipeline per level:
//   t = relu(conv3x3(feat) + conv_b)          (256->256, SAME)
//   [cls(2); mean(20); lstd(20); wgt(5)] = proj(t)  (47x256 fused matrix)
//   sample = mean + exp(lstd)*eps; cw = softmax((gumbel(u)+wgt)/0.1)
//   bbox[j] = sum_k cw[k]*sample[k*4+j]
// Output layout: per b: concat over levels of [cls NHWC (2hw), bbox NHWC (4hw)].

#define WT_F   (9*256*256)   // transposed conv weights, floats
#define PW_F   (256*48)      // fused projection weights, floats
#define TOTAL_PER_B 537138L  // 6 * (67200+16800+4200+1050+273)

__global__ void prep_kernel(const float* __restrict__ conv_w,
                            const float* __restrict__ cls_w,
                            const float* __restrict__ off_w,
                            float* __restrict__ wt,
                            float* __restrict__ projw)
{
    int idx = blockIdx.x * 256 + threadIdx.x;
    if (idx < WT_F) {
        int tap = idx >> 16;          // 0..8
        int c = (idx >> 8) & 255;
        int o = idx & 255;
        // conv_w is (O,I,3,3): [(o*256 + c)*9 + tap]
        wt[idx] = conv_w[(o * 256 + c) * 9 + tap];
    }
    if (idx < PW_F) {
        int c = idx / 48;
        int o = idx - c * 48;
        float v = 0.f;
        if (o < 2)       v = cls_w[o * 256 + c];
        else if (o < 47) v = off_w[(o - 2) * 256 + c];
        projw[idx] = v;               // [c][o], o-padded to 48
    }
}

// Conv tile: OCT=16*OCPT output channels x (8 rows x 16 cols) pixels.
// 256 threads: tid = ocg*16 + pr*2 + pc2. Each thread: OCPT oc x 8 cols (one row).
template<int OCPT>
__global__ __launch_bounds__(256, 2) void conv_relu_kernel(
    const float* __restrict__ feat,   // (2,256,H,W)
    const float* __restrict__ wt,     // (9,256,256)  [tap][c][o]
    const float* __restrict__ bias,   // (256)
    float* __restrict__ tout,         // (2,256,rows_eff,W) chunk buffer
    int H, int W, int row0, int rows_eff)
{
    const int OCT = OCPT * 16;
    const int tid = threadIdx.x;
    const int ocg = tid >> 4;         // 0..15
    const int pr  = (tid >> 1) & 7;   // 0..7 (row within tile)
    const int pc2 = tid & 1;          // 0..1 (col block of 8)
    const int x0  = blockIdx.x * 16;
    const int ty0 = row0 + blockIdx.y * 8;
    const int nz  = 256 / OCT;
    const int b   = blockIdx.z / nz;
    const int ocb = (blockIdx.z % nz) * OCT;

    __shared__ __align__(16) float xs[8][10][20]; // 8 ch x (8+2) rows x (16+2 ->pad 20) cols

    float acc[OCPT][8];
    #pragma unroll
    for (int i = 0; i < OCPT; i++)
        #pragma unroll
        for (int j = 0; j < 8; j++) acc[i][j] = 0.f;

    const long hw = (long)H * W;
    const float* fb = feat + (long)b * 256 * hw;

    #pragma unroll 1
    for (int c0 = 0; c0 < 256; c0 += 8) {
        __syncthreads();
        // stage 8 x 10 x 18 input patch, zero-filled halo
        #pragma unroll
        for (int e0 = 0; e0 < 1440; e0 += 256) {
            int e = e0 + tid;
            if (e < 1440) {
                int c = e / 180;
                int rem = e - c * 180;
                int r = rem / 18;
                int col = rem - r * 18;
                int gr = ty0 + r - 1;
                int gc = x0 + col - 1;
                float v = 0.f;
                if (gr >= 0 && gr < H && gc >= 0 && gc < W)
                    v = fb[(long)(c0 + c) * hw + (long)gr * W + gc];
                xs[c][r][col] = v;
            }
        }
        __syncthreads();
        #pragma unroll 2
        for (int cc = 0; cc < 8; cc++) {
            const float* wrow = wt + (c0 + cc) * 256 + ocb + ocg * OCPT;
            #pragma unroll
            for (int dy = 0; dy < 3; dy++) {
                float a[12];
                float4 a0 = *(const float4*)&xs[cc][pr + dy][pc2 * 8];
                float4 a1 = *(const float4*)&xs[cc][pr + dy][pc2 * 8 + 4];
                float4 a2 = *(const float4*)&xs[cc][pr + dy][pc2 * 8 + 8];
                a[0]=a0.x; a[1]=a0.y; a[2]=a0.z; a[3]=a0.w;
                a[4]=a1.x; a[5]=a1.y; a[6]=a1.z; a[7]=a1.w;
                a[8]=a2.x; a[9]=a2.y; a[10]=a2.z; a[11]=a2.w;
                #pragma unroll
                for (int dx = 0; dx < 3; dx++) {
                    const float* wp = wrow + (dy * 3 + dx) * 65536;
                    float wv[OCPT];
                    if (OCPT == 8) {
                        float4 w0 = *(const float4*)wp;
                        float4 w1 = *(const float4*)(wp + 4);
                        wv[0]=w0.x; wv[1]=w0.y; wv[2]=w0.z; wv[3]=w0.w;
                        wv[4]=w1.x; wv[5]=w1.y; wv[6]=w1.z; wv[7]=w1.w;
                    } else {
                        float2 w0 = *(const float2*)wp;
                        wv[0]=w0.x; wv[1]=w0.y;
                    }
                    #pragma unroll
                    for (int i = 0; i < OCPT; i++)
                        #pragma unroll
                        for (int j = 0; j < 8; j++)
                            acc[i][j] = fmaf(wv[i], a[dx + j], acc[i][j]);
                }
            }
        }
    }

    int orow = ty0 + pr;
    if (orow < H && (orow - row0) < rows_eff) {
        int lr = orow - row0;
        int xb = x0 + pc2 * 8;
        #pragma unroll
        for (int i = 0; i < OCPT; i++) {
            int oc = ocb + ocg * OCPT + i;
            float bv = bias[oc];
            float* dst = tout + ((long)(b * 256 + oc) * rows_eff + lr) * W + xb;
            #pragma unroll
            for (int j = 0; j < 8; j++)
                if (xb + j < W) dst[j] = fmaxf(acc[i][j] + bv, 0.f);
        }
    }
}

// Fused projection + sampling + gumbel softmax + bbox + output layout.
// One thread per pixel (of this row-chunk), both batches.
__global__ __launch_bounds__(256, 2) void proj_kernel(
    const float* __restrict__ t,      // (2,256,rows_eff,W)
    const float* __restrict__ projw,  // (256,48) [c][o]
    const float* __restrict__ cls_b,  // (2)
    const float* __restrict__ off_b,  // (45)
    const float* __restrict__ eps,    // (2,20,H,W)
    const float* __restrict__ gum,    // (2,5,H,W)
    float* __restrict__ out,
    int H, int W, int row0, int rows_eff, long lvl_off)
{
    __shared__ float4 ws4[3072];      // 48KB: 256 rows x 12 float4
    const float4* pw4 = (const float4*)projw;
    for (int e = threadIdx.x; e < 3072; e += 256) ws4[e] = pw4[e];
    __syncthreads();

    int npx = 2 * rows_eff * W;
    int lin = blockIdx.x * 256 + threadIdx.x;
    if (lin >= npx) return;
    int x = lin % W;
    int tmp = lin / W;
    int r = tmp % rows_eff;
    int b = tmp / rows_eff;
    int y = row0 + r;

    long cs = (long)rows_eff * W;
    const float* tb = t + (long)b * 256 * cs + (long)r * W + x;

    float acc[48];
    #pragma unroll
    for (int o = 0; o < 48; o++) acc[o] = 0.f;

    #pragma unroll 4
    for (int c = 0; c < 256; c++) {
        float tv = tb[(long)c * cs];
        const float4* wr = &ws4[c * 12];
        #pragma unroll
        for (int o4 = 0; o4 < 12; o4++) {
            float4 w = wr[o4];
            acc[o4*4+0] = fmaf(tv, w.x, acc[o4*4+0]);
            acc[o4*4+1] = fmaf(tv, w.y, acc[o4*4+1]);
            acc[o4*4+2] = fmaf(tv, w.z, acc[o4*4+2]);
            acc[o4*4+3] = fmaf(tv, w.w, acc[o4*4+3]);
        }
    }

    long ehw = (long)H * W;
    long pix = (long)y * W + x;
    const float* eb = eps + (long)b * 20 * ehw + pix;
    const float* gb = gum + (long)b * 5 * ehw + pix;

    // gumbel + softmax over K=5 (TEMP=0.1 -> x10)
    float wlog[5];
    float m = -1e30f;
    #pragma unroll
    for (int k = 0; k < 5; k++) {
        float u = gb[(long)k * ehw];
        float g = -logf(-logf(u + 1e-10f) + 1e-10f);
        wlog[k] = (g + acc[42 + k] + off_b[40 + k]) * 10.0f;
        m = fmaxf(m, wlog[k]);
    }
    float s = 0.f, cw[5];
    #pragma unroll
    for (int k = 0; k < 5; k++) { cw[k] = expf(wlog[k] - m); s += cw[k]; }
    float inv = 1.0f / s;

    float bbox[4] = {0.f, 0.f, 0.f, 0.f};
    #pragma unroll
    for (int k = 0; k < 5; k++) {
        float cwk = cw[k] * inv;
        #pragma unroll
        for (int j = 0; j < 4; j++) {
            int kj = k * 4 + j;
            float mean = acc[2 + kj]  + off_b[kj];
            float lstd = acc[22 + kj] + off_b[20 + kj];
            float sv = fmaf(expf(lstd), eb[(long)kj * ehw], mean);
            bbox[j] = fmaf(cwk, sv, bbox[j]);
        }
    }

    float* ob = out + (long)b * TOTAL_PER_B + lvl_off;
    ob[pix * 2 + 0] = acc[0] + cls_b[0];
    ob[pix * 2 + 1] = acc[1] + cls_b[1];
    float* o2 = ob + ehw * 2 + pix * 4;
    o2[0] = bbox[0]; o2[1] = bbox[1]; o2[2] = bbox[2]; o2[3] = bbox[3];
}

extern "C" void kernel_launch(void* const* d_in, const int* in_sizes, int n_in,
                              void* d_out, int out_size, void* d_ws, size_t ws_size,
                              hipStream_t stream)
{
    static const int LH[5] = {200, 100, 50, 25, 13};
    static const int LW[5] = {336, 168, 84, 42, 21};

    const float* conv_w = (const float*)d_in[15];
    const float* conv_b = (const float*)d_in[16];
    const float* cls_w  = (const float*)d_in[17];
    const float* cls_b  = (const float*)d_in[18];
    const float* off_w  = (const float*)d_in[19];
    const float* off_b  = (const float*)d_in[20];

    float* wt    = (float*)d_ws;
    float* projw = wt + WT_F;
    float* tbuf  = projw + PW_F;
    long tavail = ((long)ws_size - (long)(WT_F + PW_F) * 4) / 4; // floats for t chunk

    prep_kernel<<<(WT_F + 255) / 256, 256, 0, stream>>>(conv_w, cls_w, off_w, wt, projw);

    long lvl_off = 0;
    for (int l = 0; l < 5; l++) {
        int H = LH[l], W = LW[l];
        const float* feat = (const float*)d_in[3 * l];
        const float* eps  = (const float*)d_in[3 * l + 1];
        const float* gum  = (const float*)d_in[3 * l + 2];

        long per_row = 2L * 256 * W;                 // floats per image row of t
        int maxrows = (int)(tavail / per_row);
        if (maxrows >= H) maxrows = H;
        else { maxrows &= ~7; if (maxrows < 8) maxrows = 8; }

        for (int row0 = 0; row0 < H; row0 += maxrows) {
            int rows_eff = H - row0;
            if (rows_eff > maxrows) rows_eff = maxrows;

            unsigned gy = (unsigned)((rows_eff + 7) / 8);
            unsigned gx = (unsigned)((W + 15) / 16);
            if (l < 2) {
                dim3 cgrid(gx, gy, 4);   // b*2 + oc-chunk(128)
                conv_relu_kernel<8><<<cgrid, 256, 0, stream>>>(
                    feat, wt, conv_b, tbuf, H, W, row0, rows_eff);
            } else {
                dim3 cgrid(gx, gy, 16);  // b*8 + oc-chunk(32): more blocks for small levels
                conv_relu_kernel<2><<<cgrid, 256, 0, stream>>>(
                    feat, wt, conv_b, tbuf, H, W, row0, rows_eff);
            }

            int npx = 2 * rows_eff * W;
            proj_kernel<<<dim3((unsigned)((npx + 255) / 256)), 256, 0, stream>>>(
                tbuf, projw, cls_b, off_b, eps, gum, (float*)d_out,
                H, W, row0, rows_eff, lvl_off);
        }
        lvl_off += 6L * H * W;
    }
}

// Round 2
// 1989.604 us; speedup vs baseline: 2.2824x; 2.2824x over previous
//
#include <hip/hip_runtime.h>

// RPN head, 5 FPN levels.
//   t = relu(conv3x3(feat) + conv_b)          (256->256, SAME)  -> bf16-MFMA implicit GEMM
//   [cls(2); mean(20); lstd(20); wgt(5)] = proj(t)  (47x256 fused matrix)
//   sample = mean + exp(lstd)*eps; cw = softmax((gumbel(u)+wgt)/0.1)
//   bbox[j] = sum_k cw[k]*sample[k*4+j]
// Conv uses split-bf16 (hi/lo) 3-term MFMA => fp32-equivalent accuracy on the matrix pipe.

#define WT_F   (9*256*256)   // conv weight elements (per hi/lo bf16 array)
#define PW_F   (256*48)      // fused projection weights, floats
#define TOTAL_PER_B 537138L  // 6 * (67200+16800+4200+1050+273)

typedef __attribute__((ext_vector_type(8))) short short8;
typedef __attribute__((ext_vector_type(16))) float f32x16;

__device__ __forceinline__ unsigned short f2bf(float f) {
    union { float f; unsigned u; } v; v.f = f;
    unsigned u = v.u;
    u += 0x7fffu + ((u >> 16) & 1u);   // RNE
    return (unsigned short)(u >> 16);
}
__device__ __forceinline__ float bf2f(unsigned short h) {
    union { unsigned u; float f; } v; v.u = ((unsigned)h) << 16;
    return v.f;
}

__global__ void prep_kernel(const float* __restrict__ conv_w,
                            const float* __restrict__ cls_w,
                            const float* __restrict__ off_w,
                            unsigned short* __restrict__ wAhi,  // [tap][oc][c]
                            unsigned short* __restrict__ wAlo,
                            float* __restrict__ projw)
{
    int idx = blockIdx.x * 256 + threadIdx.x;
    if (idx < WT_F) {
        int tap = idx >> 16;          // idx = tap*65536 + oc*256 + c
        int oc  = (idx >> 8) & 255;
        int c   = idx & 255;
        float w = conv_w[(oc * 256 + c) * 9 + tap];
        unsigned short h = f2bf(w);
        wAhi[idx] = h;
        wAlo[idx] = f2bf(w - bf2f(h));
    }
    if (idx < PW_F) {
        int c = idx / 48;
        int o = idx - c * 48;
        float v = 0.f;
        if (o < 2)       v = cls_w[o * 256 + c];
        else if (o < 47) v = off_w[(o - 2) * 256 + c];
        projw[idx] = v;               // [c][o], o-padded to 48
    }
}

// Implicit-GEMM conv: M=oc(128/block), N=pixels(8 rows x 16 cols), K=256c*9taps.
// 4 waves: 2(oc) x 2(px-rows). Wave tile 64oc x 64px = 2x2 frags of 32x32.
// A (weights) from global [tap][oc][c] bf16; B (feat) from LDS [pos][c] bf16,
// row stride 40 bf16 (80B) for bank-uniform ds_read_b128.
__global__ __launch_bounds__(256, 2) void conv_mfma_kernel(
    const float* __restrict__ feat,            // (2,256,H,W) fp32
    const unsigned short* __restrict__ wAhi,   // (9,256,256) bf16
    const unsigned short* __restrict__ wAlo,
    const float* __restrict__ bias,            // (256)
    float* __restrict__ tout,                  // (2,256,rows_eff,W) fp32 chunk
    int H, int W, int row0, int rows_eff)
{
    __shared__ __align__(16) unsigned short sh[2 * 180 * 40]; // hi | lo, 180 pos x 40 bf16
    unsigned short* shi = sh;
    unsigned short* slo = sh + 180 * 40;

    const int tid  = threadIdx.x;
    const int lane = tid & 63;
    const int wid  = tid >> 6;
    const int x0   = blockIdx.x * 16;
    const int ty0  = row0 + blockIdx.y * 8;
    const int b    = blockIdx.z >> 1;
    const int ocb  = (blockIdx.z & 1) * 128;

    const long hw = (long)H * W;
    const float* fb = feat + (long)b * 256 * hw;

    const int woc = (wid >> 1) * 64;   // wave oc base within block's 128
    const int wpr = (wid & 1) * 4;     // wave pixel-row base (4 rows x 16 cols = 64 px)
    const int rin = (lane & 31) >> 4;  // row within 32-px fragment
    const int cin = lane & 15;         // col within fragment
    const int kg  = lane >> 5;         // k-group (8 channels)

    f32x16 acc00 = {}, acc01 = {}, acc10 = {}, acc11 = {}; // acc[of][pf]

    for (int c0 = 0; c0 < 256; c0 += 32) {
        __syncthreads();
        // stage 32 channels x 10x18 halo tile, fp32 -> bf16 hi/lo, [pos][c] layout
        for (int e = tid; e < 2880; e += 256) {
            int cpair = e / 180;          // 16 channel-pairs
            int pos   = e - cpair * 180;
            int r     = pos / 18;
            int col   = pos - r * 18;
            int gr = ty0 + r - 1;
            int gc = x0 + col - 1;
            float f0 = 0.f, f1 = 0.f;
            if (gr >= 0 && gr < H && gc >= 0 && gc < W) {
                const float* p = fb + (long)(c0 + cpair * 2) * hw + (long)gr * W + gc;
                f0 = p[0];
                f1 = p[hw];
            }
            unsigned short h0 = f2bf(f0), h1 = f2bf(f1);
            unsigned short l0 = f2bf(f0 - bf2f(h0));
            unsigned short l1 = f2bf(f1 - bf2f(h1));
            ((unsigned*)shi)[pos * 20 + cpair] = (unsigned)h0 | ((unsigned)h1 << 16);
            ((unsigned*)slo)[pos * 20 + cpair] = (unsigned)l0 | ((unsigned)l1 << 16);
        }
        __syncthreads();

        #pragma unroll
        for (int tap = 0; tap < 9; tap++) {
            const int dy = tap / 3;
            const int dx = tap - dy * 3;
            #pragma unroll
            for (int ks = 0; ks < 2; ks++) {
                const int coff = c0 + ks * 16 + kg * 8;          // channel base for this lane
                const long wo = (long)tap * 65536 + (long)(ocb + woc + (lane & 31)) * 256 + coff;
                short8 ah0 = *(const short8*)(wAhi + wo);
                short8 ah1 = *(const short8*)(wAhi + wo + 32 * 256);
                short8 al0 = *(const short8*)(wAlo + wo);
                short8 al1 = *(const short8*)(wAlo + wo + 32 * 256);

                const int lidx = ks * 16 + kg * 8;               // ushort offset within pos row
                const int p0 = (wpr + 0 + rin + dy) * 18 + cin + dx;
                const int p1 = (wpr + 2 + rin + dy) * 18 + cin + dx;
                short8 bh0 = *(const short8*)(shi + p0 * 40 + lidx);
                short8 bh1 = *(const short8*)(shi + p1 * 40 + lidx);
                short8 bl0 = *(const short8*)(slo + p0 * 40 + lidx);
                short8 bl1 = *(const short8*)(slo + p1 * 40 + lidx);

                // hi*hi
                acc00 = __builtin_amdgcn_mfma_f32_32x32x16_bf16(ah0, bh0, acc00, 0, 0, 0);
                acc01 = __builtin_amdgcn_mfma_f32_32x32x16_bf16(ah0, bh1, acc01, 0, 0, 0);
                acc10 = __builtin_amdgcn_mfma_f32_32x32x16_bf16(ah1, bh0, acc10, 0, 0, 0);
                acc11 = __builtin_amdgcn_mfma_f32_32x32x16_bf16(ah1, bh1, acc11, 0, 0, 0);
                // hi*lo
                acc00 = __builtin_amdgcn_mfma_f32_32x32x16_bf16(ah0, bl0, acc00, 0, 0, 0);
                acc01 = __builtin_amdgcn_mfma_f32_32x32x16_bf16(ah0, bl1, acc01, 0, 0, 0);
                acc10 = __builtin_amdgcn_mfma_f32_32x32x16_bf16(ah1, bl0, acc10, 0, 0, 0);
                acc11 = __builtin_amdgcn_mfma_f32_32x32x16_bf16(ah1, bl1, acc11, 0, 0, 0);
                // lo*hi
                acc00 = __builtin_amdgcn_mfma_f32_32x32x16_bf16(al0, bh0, acc00, 0, 0, 0);
                acc01 = __builtin_amdgcn_mfma_f32_32x32x16_bf16(al0, bh1, acc01, 0, 0, 0);
                acc10 = __builtin_amdgcn_mfma_f32_32x32x16_bf16(al1, bh0, acc10, 0, 0, 0);
                acc11 = __builtin_amdgcn_mfma_f32_32x32x16_bf16(al1, bh1, acc11, 0, 0, 0);
            }
        }
    }

    // epilogue: bias + relu + store. C/D: col(pixel)=lane&31, row(oc)=(r&3)+8*(r>>2)+4*kg
    const int x = x0 + cin;
    const int lrb = (ty0 - row0) + wpr;
    #pragma unroll
    for (int of = 0; of < 2; of++) {
        #pragma unroll
        for (int pf = 0; pf < 2; pf++) {
            const f32x16 a = (of == 0) ? (pf == 0 ? acc00 : acc01)
                                       : (pf == 0 ? acc10 : acc11);
            const int lr = lrb + pf * 2 + rin;
            if (lr < rows_eff && x < W) {
                #pragma unroll
                for (int rg = 0; rg < 16; rg++) {
                    int oc = ocb + woc + of * 32 + (rg & 3) + 8 * (rg >> 2) + 4 * kg;
                    float v = a[rg] + bias[oc];
                    tout[((long)(b * 256 + oc) * rows_eff + lr) * W + x] = fmaxf(v, 0.f);
                }
            }
        }
    }
}

// Fused projection + sampling + gumbel softmax + bbox + output layout (unchanged).
__global__ __launch_bounds__(256, 2) void proj_kernel(
    const float* __restrict__ t,      // (2,256,rows_eff,W)
    const float* __restrict__ projw,  // (256,48) [c][o]
    const float* __restrict__ cls_b,  // (2)
    const float* __restrict__ off_b,  // (45)
    const float* __restrict__ eps,    // (2,20,H,W)
    const float* __restrict__ gum,    // (2,5,H,W)
    float* __restrict__ out,
    int H, int W, int row0, int rows_eff, long lvl_off)
{
    __shared__ float4 ws4[3072];      // 48KB: 256 rows x 12 float4
    const float4* pw4 = (const float4*)projw;
    for (int e = threadIdx.x; e < 3072; e += 256) ws4[e] = pw4[e];
    __syncthreads();

    int npx = 2 * rows_eff * W;
    int lin = blockIdx.x * 256 + threadIdx.x;
    if (lin >= npx) return;
    int x = lin % W;
    int tmp = lin / W;
    int r = tmp % rows_eff;
    int b = tmp / rows_eff;
    int y = row0 + r;

    long cs = (long)rows_eff * W;
    const float* tb = t + (long)b * 256 * cs + (long)r * W + x;

    float acc[48];
    #pragma unroll
    for (int o = 0; o < 48; o++) acc[o] = 0.f;

    #pragma unroll 4
    for (int c = 0; c < 256; c++) {
        float tv = tb[(long)c * cs];
        const float4* wr = &ws4[c * 12];
        #pragma unroll
        for (int o4 = 0; o4 < 12; o4++) {
            float4 w = wr[o4];
            acc[o4*4+0] = fmaf(tv, w.x, acc[o4*4+0]);
            acc[o4*4+1] = fmaf(tv, w.y, acc[o4*4+1]);
            acc[o4*4+2] = fmaf(tv, w.z, acc[o4*4+2]);
            acc[o4*4+3] = fmaf(tv, w.w, acc[o4*4+3]);
        }
    }

    long ehw = (long)H * W;
    long pix = (long)y * W + x;
    const float* eb = eps + (long)b * 20 * ehw + pix;
    const float* gb = gum + (long)b * 5 * ehw + pix;

    float wlog[5];
    float m = -1e30f;
    #pragma unroll
    for (int k = 0; k < 5; k++) {
        float u = gb[(long)k * ehw];
        float g = -logf(-logf(u + 1e-10f) + 1e-10f);
        wlog[k] = (g + acc[42 + k] + off_b[40 + k]) * 10.0f;
        m = fmaxf(m, wlog[k]);
    }
    float s = 0.f, cw[5];
    #pragma unroll
    for (int k = 0; k < 5; k++) { cw[k] = expf(wlog[k] - m); s += cw[k]; }
    float inv = 1.0f / s;

    float bbox[4] = {0.f, 0.f, 0.f, 0.f};
    #pragma unroll
    for (int k = 0; k < 5; k++) {
        float cwk = cw[k] * inv;
        #pragma unroll
        for (int j = 0; j < 4; j++) {
            int kj = k * 4 + j;
            float mean = acc[2 + kj]  + off_b[kj];
            float lstd = acc[22 + kj] + off_b[20 + kj];
            float sv = fmaf(expf(lstd), eb[(long)kj * ehw], mean);
            bbox[j] = fmaf(cwk, sv, bbox[j]);
        }
    }

    float* ob = out + (long)b * TOTAL_PER_B + lvl_off;
    ob[pix * 2 + 0] = acc[0] + cls_b[0];
    ob[pix * 2 + 1] = acc[1] + cls_b[1];
    float* o2 = ob + ehw * 2 + pix * 4;
    o2[0] = bbox[0]; o2[1] = bbox[1]; o2[2] = bbox[2]; o2[3] = bbox[3];
}

extern "C" void kernel_launch(void* const* d_in, const int* in_sizes, int n_in,
                              void* d_out, int out_size, void* d_ws, size_t ws_size,
                              hipStream_t stream)
{
    static const int LH[5] = {200, 100, 50, 25, 13};
    static const int LW[5] = {336, 168, 84, 42, 21};

    const float* conv_w = (const float*)d_in[15];
    const float* conv_b = (const float*)d_in[16];
    const float* cls_w  = (const float*)d_in[17];
    const float* cls_b  = (const float*)d_in[18];
    const float* off_w  = (const float*)d_in[19];
    const float* off_b  = (const float*)d_in[20];

    unsigned short* wAhi = (unsigned short*)d_ws;
    unsigned short* wAlo = wAhi + WT_F;
    float* projw = (float*)(wAlo + WT_F);          // byte offset WT_F*4 (same as old fp32 wt)
    float* tbuf  = projw + PW_F;
    long tavail = ((long)ws_size - (long)(WT_F + PW_F) * 4) / 4; // floats for t chunk

    prep_kernel<<<(WT_F + 255) / 256, 256, 0, stream>>>(conv_w, cls_w, off_w, wAhi, wAlo, projw);

    long lvl_off = 0;
    for (int l = 0; l < 5; l++) {
        int H = LH[l], W = LW[l];
        const float* feat = (const float*)d_in[3 * l];
        const float* eps  = (const float*)d_in[3 * l + 1];
        const float* gum  = (const float*)d_in[3 * l + 2];

        long per_row = 2L * 256 * W;                 // floats per image row of t
        int maxrows = (int)(tavail / per_row);
        if (maxrows >= H) maxrows = H;
        else { maxrows &= ~7; if (maxrows < 8) maxrows = 8; }

        for (int row0 = 0; row0 < H; row0 += maxrows) {
            int rows_eff = H - row0;
            if (rows_eff > maxrows) rows_eff = maxrows;

            dim3 cgrid((unsigned)((W + 15) / 16), (unsigned)((rows_eff + 7) / 8), 4);
            conv_mfma_kernel<<<cgrid, 256, 0, stream>>>(
                feat, wAhi, wAlo, conv_b, tbuf, H, W, row0, rows_eff);

            int npx = 2 * rows_eff * W;
            proj_kernel<<<dim3((unsigned)((npx + 255) / 256)), 256, 0, stream>>>(
                tbuf, projw, cls_b, off_b, eps, gum, (float*)d_out,
                H, W, row0, rows_eff, lvl_off);
        }
        lvl_off += 6L * H * W;
    }
}

// Round 3
// 909.318 us; speedup vs baseline: 4.9940x; 2.1880x over previous
//
#include <hip/hip_runtime.h>

// RPN head, 5 FPN levels, 3 launches total:
//   prep:     conv weights -> fp16 hi/lo in [tap][cg][oc][8c] (coalesced A-loads),
//             proj weights fused to [c][48] fp32
//   conv_all: t = relu(conv3x3(feat)+b) for ALL levels, implicit-GEMM on
//             v_mfma_f32_32x32x16_f16; A 2-term (hi+lo), B single fp16.
//             Block = 256oc x 128px (4 waves x 64oc), t stored fp16.
//   proj_all: 47x256 projection + reparam sample + gumbel softmax + bbox,
//             NHWC outputs for ALL levels.

#define WT_F   (9*256*256)   // conv weight elements per (hi|lo) array
#define PW_F   (256*48)
#define TOTAL_PER_B 537138L
#define TOTAL_PX 179046      // sum over levels of 2*H*W

typedef __attribute__((ext_vector_type(8))) _Float16 half8;
typedef __attribute__((ext_vector_type(16))) float f32x16;

struct ConvParams {
    const float* feat[5];
    long  toff[5];
    int   Hs[5], Ws[5], gxs[5], cum[5];
};
struct ProjParams {
    const float* eps[5];
    const float* gum[5];
    long  toff[5], loff[5], pxcum[5];
    int   Hs[5], Ws[5];
};

__device__ __forceinline__ unsigned short h2u(_Float16 h) {
    union { _Float16 h; unsigned short u; } v; v.h = h; return v.u;
}

__global__ void prep_kernel(const float* __restrict__ conv_w,
                            const float* __restrict__ cls_w,
                            const float* __restrict__ off_w,
                            _Float16* __restrict__ wh,
                            _Float16* __restrict__ wl,
                            float* __restrict__ projw)
{
    int t = blockIdx.x * 256 + threadIdx.x;
    if (t < 8192) {                       // one thread per (oc, cg): 256*32
        int oc = t >> 5, cg = t & 31;
        const float4* s4 = (const float4*)(conv_w + ((long)oc * 256 + cg * 8) * 9);
        float w[72];
        #pragma unroll
        for (int i = 0; i < 18; i++) {
            float4 v = s4[i];
            w[i*4+0] = v.x; w[i*4+1] = v.y; w[i*4+2] = v.z; w[i*4+3] = v.w;
        }
        #pragma unroll
        for (int tap = 0; tap < 9; tap++) {
            half8 hv, lv;
            #pragma unroll
            for (int i = 0; i < 8; i++) {
                float x = w[i * 9 + tap];
                _Float16 h = (_Float16)x;
                hv[i] = h;
                lv[i] = (_Float16)(x - (float)h);
            }
            long o = ((long)(tap * 32 + cg) * 256 + oc) * 8;
            *(half8*)(wh + o) = hv;
            *(half8*)(wl + o) = lv;
        }
    }
    if (t < PW_F) {
        int c = t / 48;
        int o = t - c * 48;
        float v = 0.f;
        if (o < 2)       v = cls_w[o * 256 + c];
        else if (o < 47) v = off_w[(o - 2) * 256 + c];
        projw[t] = v;
    }
}

// Implicit-GEMM conv for all levels. Block: 256oc x (8 rows x 16 cols) px.
// 4 waves split oc (64 each); per wave: 2 oc-frags x 4 px-frags of 32x32.
// A (fp16 hi/lo) from global, coalesced [tap][cg][oc][8]; B (fp16) from LDS.
__global__ __launch_bounds__(256, 2) void conv_all_kernel(
    ConvParams P,
    const _Float16* __restrict__ wh,
    const _Float16* __restrict__ wl,
    const float* __restrict__ bias,
    _Float16* __restrict__ tbuf)
{
    // level decode (block-uniform)
    int tb = blockIdx.x;
    int l = 0;
    #pragma unroll
    for (int i = 0; i < 5; i++) if (tb >= P.cum[i]) l = i + 1;
    int prev = l ? P.cum[l - 1] : 0;
    int rem = tb - prev;
    const int gx = P.gxs[l];
    const int ty = rem / gx;
    const int tx = rem - ty * gx;
    const int H = P.Hs[l], W = P.Ws[l];
    const long hw = (long)H * W;
    const float* feat = P.feat[l];
    _Float16* tout = tbuf + P.toff[l];

    __shared__ __align__(16) _Float16 sB[180 * 40];  // 10x18 pos x 32c (+8 pad)

    const int tid  = threadIdx.x;
    const int lane = tid & 63;
    const int wid  = tid >> 6;
    const int x0   = tx * 16;
    const int ty0  = ty * 8;
    const int b    = blockIdx.z;

    const int woc = wid * 64;
    const int lr32 = lane & 31;
    const int rin = lr32 >> 4;
    const int cin = lane & 15;
    const int kg  = lane >> 5;

    const float* fb = feat + (long)b * 256 * hw;

    f32x16 acc0[4] = {}, acc1[4] = {};   // [oc-frag][px-frag]

    for (int c0 = 0; c0 < 256; c0 += 32) {
        __syncthreads();
        // stage 32 ch x 10x18 halo tile as fp16, [pos][c] (pairs packed per dword)
        for (int e = tid; e < 2880; e += 256) {
            int cpair = e / 180;
            int pos   = e - cpair * 180;
            int r     = pos / 18;
            int col   = pos - r * 18;
            int gr = ty0 + r - 1;
            int gc = x0 + col - 1;
            float f0 = 0.f, f1 = 0.f;
            if (gr >= 0 && gr < H && gc >= 0 && gc < W) {
                const float* p = fb + (long)(c0 + cpair * 2) * hw + (long)gr * W + gc;
                f0 = p[0];
                f1 = p[hw];
            }
            ((unsigned*)sB)[pos * 20 + cpair] =
                (unsigned)h2u((_Float16)f0) | ((unsigned)h2u((_Float16)f1) << 16);
        }
        __syncthreads();

        #pragma unroll
        for (int tap = 0; tap < 9; tap++) {
            const int dy = tap / 3;
            const int dx = tap - dy * 3;
            #pragma unroll
            for (int ks = 0; ks < 2; ks++) {
                const int cgt = (c0 >> 3) + ks * 2 + kg;
                const long ao = ((long)(tap * 32 + cgt) * 256 + woc + lr32) * 8;
                half8 ah0 = *(const half8*)(wh + ao);
                half8 ah1 = *(const half8*)(wh + ao + 256);   // +32 oc
                half8 al0 = *(const half8*)(wl + ao);
                half8 al1 = *(const half8*)(wl + ao + 256);
                const int boff = ks * 16 + kg * 8;
                #pragma unroll
                for (int pf = 0; pf < 4; pf++) {
                    const int pos = (2 * pf + rin + dy) * 18 + cin + dx;
                    half8 bv = *(const half8*)(sB + pos * 40 + boff);
                    acc0[pf] = __builtin_amdgcn_mfma_f32_32x32x16_f16(ah0, bv, acc0[pf], 0, 0, 0);
                    acc1[pf] = __builtin_amdgcn_mfma_f32_32x32x16_f16(ah1, bv, acc1[pf], 0, 0, 0);
                    acc0[pf] = __builtin_amdgcn_mfma_f32_32x32x16_f16(al0, bv, acc0[pf], 0, 0, 0);
                    acc1[pf] = __builtin_amdgcn_mfma_f32_32x32x16_f16(al1, bv, acc1[pf], 0, 0, 0);
                }
            }
        }
    }

    // epilogue: bias+relu, store fp16. C/D: col(px)=lane&31, row(oc)=(rg&3)+8*(rg>>2)+4*kg
    const int x = x0 + cin;
    if (x < W) {
        #pragma unroll
        for (int of = 0; of < 2; of++) {
            #pragma unroll
            for (int pf = 0; pf < 4; pf++) {
                const f32x16 a = of == 0 ? acc0[pf] : acc1[pf];
                const int row = ty0 + 2 * pf + rin;
                if (row < H) {
                    #pragma unroll
                    for (int rg = 0; rg < 16; rg++) {
                        int oc = woc + of * 32 + (rg & 3) + 8 * (rg >> 2) + 4 * kg;
                        float v = a[rg] + bias[oc];
                        tout[((long)(b * 256 + oc) * H + row) * W + x] =
                            (_Float16)fmaxf(v, 0.f);
                    }
                }
            }
        }
    }
}

// Projection + sampling + gumbel softmax + bbox for ALL levels, one thread/px.
__global__ __launch_bounds__(256, 2) void proj_all_kernel(
    ProjParams P,
    const _Float16* __restrict__ tbuf,
    const float* __restrict__ projw,
    const float* __restrict__ cls_b,
    const float* __restrict__ off_b,
    float* __restrict__ out)
{
    __shared__ float4 ws4[3072];      // 48KB: 256 rows x 12 float4
    const float4* pw4 = (const float4*)projw;
    for (int e = threadIdx.x; e < 3072; e += 256) ws4[e] = pw4[e];
    __syncthreads();

    int lin = blockIdx.x * 256 + threadIdx.x;
    if (lin >= TOTAL_PX) return;

    int l = 0;
    #pragma unroll
    for (int i = 0; i < 5; i++) if (lin >= P.pxcum[i]) l = i + 1;
    long base = l ? P.pxcum[l - 1] : 0;
    long p = lin - base;
    const int H = P.Hs[l], W = P.Ws[l];
    const long hw = (long)H * W;
    int x = (int)(p % W);
    long tmp = p / W;
    int r = (int)(tmp % H);
    int b = (int)(tmp / H);

    const _Float16* tb = tbuf + P.toff[l] + (long)b * 256 * hw + (long)r * W + x;

    float acc[48];
    #pragma unroll
    for (int o = 0; o < 48; o++) acc[o] = 0.f;

    #pragma unroll 4
    for (int c = 0; c < 256; c++) {
        float tv = (float)tb[(long)c * hw];
        const float4* wr = &ws4[c * 12];
        #pragma unroll
        for (int o4 = 0; o4 < 12; o4++) {
            float4 w = wr[o4];
            acc[o4*4+0] = fmaf(tv, w.x, acc[o4*4+0]);
            acc[o4*4+1] = fmaf(tv, w.y, acc[o4*4+1]);
            acc[o4*4+2] = fmaf(tv, w.z, acc[o4*4+2]);
            acc[o4*4+3] = fmaf(tv, w.w, acc[o4*4+3]);
        }
    }

    long pix = (long)r * W + x;
    const float* eb = P.eps[l] + (long)b * 20 * hw + pix;
    const float* gb = P.gum[l] + (long)b * 5 * hw + pix;

    float wlog[5];
    float m = -1e30f;
    #pragma unroll
    for (int k = 0; k < 5; k++) {
        float u = gb[(long)k * hw];
        float g = -logf(-logf(u + 1e-10f) + 1e-10f);
        wlog[k] = (g + acc[42 + k] + off_b[40 + k]) * 10.0f;
        m = fmaxf(m, wlog[k]);
    }
    float s = 0.f, cw[5];
    #pragma unroll
    for (int k = 0; k < 5; k++) { cw[k] = expf(wlog[k] - m); s += cw[k]; }
    float inv = 1.0f / s;

    float bbox[4] = {0.f, 0.f, 0.f, 0.f};
    #pragma unroll
    for (int k = 0; k < 5; k++) {
        float cwk = cw[k] * inv;
        #pragma unroll
        for (int j = 0; j < 4; j++) {
            int kj = k * 4 + j;
            float mean = acc[2 + kj]  + off_b[kj];
            float lstd = acc[22 + kj] + off_b[20 + kj];
            float sv = fmaf(expf(lstd), eb[(long)kj * hw], mean);
            bbox[j] = fmaf(cwk, sv, bbox[j]);
        }
    }

    float* ob = out + (long)b * TOTAL_PER_B + P.loff[l];
    ob[pix * 2 + 0] = acc[0] + cls_b[0];
    ob[pix * 2 + 1] = acc[1] + cls_b[1];
    float* o2 = ob + hw * 2 + pix * 4;
    o2[0] = bbox[0]; o2[1] = bbox[1]; o2[2] = bbox[2]; o2[3] = bbox[3];
}

extern "C" void kernel_launch(void* const* d_in, const int* in_sizes, int n_in,
                              void* d_out, int out_size, void* d_ws, size_t ws_size,
                              hipStream_t stream)
{
    static const int LH[5] = {200, 100, 50, 25, 13};
    static const int LW[5] = {336, 168, 84, 42, 21};

    const float* conv_w = (const float*)d_in[15];
    const float* conv_b = (const float*)d_in[16];
    const float* cls_w  = (const float*)d_in[17];
    const float* cls_b  = (const float*)d_in[18];
    const float* off_w  = (const float*)d_in[19];
    const float* off_b  = (const float*)d_in[20];

    _Float16* wh = (_Float16*)d_ws;
    _Float16* wl = wh + WT_F;
    float* projw = (float*)(wl + WT_F);
    _Float16* tbuf = (_Float16*)(projw + PW_F);

    ConvParams cp;
    ProjParams pp;
    long toff = 0, loff = 0, pxc = 0;
    int cum = 0;
    for (int l = 0; l < 5; l++) {
        int H = LH[l], W = LW[l];
        long hw = (long)H * W;
        cp.feat[l] = (const float*)d_in[3 * l];
        pp.eps[l]  = (const float*)d_in[3 * l + 1];
        pp.gum[l]  = (const float*)d_in[3 * l + 2];
        cp.toff[l] = toff; pp.toff[l] = toff;
        cp.Hs[l] = H; cp.Ws[l] = W;
        pp.Hs[l] = H; pp.Ws[l] = W;
        int gx = (W + 15) / 16, gy = (H + 7) / 8;
        cp.gxs[l] = gx;
        cum += gx * gy;
        cp.cum[l] = cum;
        pp.loff[l] = loff;
        pxc += 2 * hw;
        pp.pxcum[l] = pxc;
        toff += 2L * 256 * hw;
        loff += 6L * hw;
    }

    prep_kernel<<<48, 256, 0, stream>>>(conv_w, cls_w, off_w, wh, wl, projw);

    conv_all_kernel<<<dim3((unsigned)cum, 1, 2), 256, 0, stream>>>(
        cp, wh, wl, conv_b, tbuf);

    proj_all_kernel<<<dim3((unsigned)((TOTAL_PX + 255) / 256)), 256, 0, stream>>>(
        pp, tbuf, projw, cls_b, off_b, (float*)d_out);
}

// Round 6
// 699.936 us; speedup vs baseline: 6.4879x; 1.2991x over previous
//
#include <hip/hip_runtime.h>

// RPN head, 5 FPN levels, 3 launches:
//   prep:     conv weights -> fp16 hi/lo [tap][cg][oc][8c]; proj weights ->
//             fp16 hi/lo MFMA A-fragments [mt][ks][lane][8]
//   conv_all: t = relu(conv3x3(feat)+b), implicit GEMM on mfma_32x32x16_f16,
//             A 2-term (hi+lo), B single fp16. t stored NHWC fp16 [px][256].
//   proj_all: 48x256 projection as mfma_16x16x32_f16 (B = t, coalesced global),
//             LDS bounce, then per-px reparam sample + gumbel softmax + bbox.

#define WT_F   (9*256*256)
#define PA_F   (3*8*64*8)      // 12288 halfs per (hi|lo)
#define TOTAL_PER_B 537138L
#define NTILE  2799            // 64-px proj wave-tiles over all levels

typedef __attribute__((ext_vector_type(8))) _Float16 half8;
typedef __attribute__((ext_vector_type(4))) _Float16 half4;
typedef __attribute__((ext_vector_type(16))) float f32x16;
typedef __attribute__((ext_vector_type(4))) float f32x4;

struct ConvParams {
    const float* feat[5];
    long  toff[5];                    // halfs into tbuf (NHWC per level)
    int   Hs[5], Ws[5], gxs[5], cum[5];
};
struct ProjParams {
    const float* eps[5];
    const float* gum[5];
    long  toff[5], loff[5], hws[5];
    int   tcum[5];
};

__global__ void prep_kernel(const float* __restrict__ conv_w,
                            const float* __restrict__ cls_w,
                            const float* __restrict__ off_w,
                            _Float16* __restrict__ wh,
                            _Float16* __restrict__ wl,
                            _Float16* __restrict__ pAh,
                            _Float16* __restrict__ pAl)
{
    int t = blockIdx.x * 256 + threadIdx.x;
    if (t < 8192) {                       // (oc, cg): 256*32
        int oc = t >> 5, cg = t & 31;
        const float4* s4 = (const float4*)(conv_w + ((long)oc * 256 + cg * 8) * 9);
        float w[72];
        #pragma unroll
        for (int i = 0; i < 18; i++) {
            float4 v = s4[i];
            w[i*4+0] = v.x; w[i*4+1] = v.y; w[i*4+2] = v.z; w[i*4+3] = v.w;
        }
        #pragma unroll
        for (int tap = 0; tap < 9; tap++) {
            half8 hv, lv;
            #pragma unroll
            for (int i = 0; i < 8; i++) {
                float x = w[i * 9 + tap];
                _Float16 h = (_Float16)x;
                hv[i] = h;
                lv[i] = (_Float16)(x - (float)h);
            }
            long o = ((long)(tap * 32 + cg) * 256 + oc) * 8;
            *(half8*)(wh + o) = hv;
            *(half8*)(wl + o) = lv;
        }
    }
    if (t < 1536) {                       // proj A-frags: (mt*8+ks)*64 + lane
        int frag = t >> 6;                // 0..23
        int mt = frag >> 3, ks = frag & 7;
        int ln = t & 63;
        int m = mt * 16 + (ln & 15);
        int kb = ks * 32 + (ln >> 4) * 8;
        half8 hv, lv;
        #pragma unroll
        for (int i = 0; i < 8; i++) {
            int c = kb + i;
            float v = 0.f;
            if (m < 2)       v = cls_w[m * 256 + c];
            else if (m < 47) v = off_w[(m - 2) * 256 + c];
            _Float16 h = (_Float16)v;
            hv[i] = h;
            lv[i] = (_Float16)(v - (float)h);
        }
        *(half8*)(pAh + (long)t * 8) = hv;
        *(half8*)(pAl + (long)t * 8) = lv;
    }
}

// Conv: block = 256oc x (8 rows x 16 cols). 4 waves: oh=wid>>1 (oc half),
// ph=wid&1 (row half). Wave = 128oc x 64px: of=4 frags x pf=2 frags (32x32).
__global__ __launch_bounds__(256, 2) void conv_all_kernel(
    ConvParams P,
    const _Float16* __restrict__ wh,
    const _Float16* __restrict__ wl,
    const float* __restrict__ bias,
    _Float16* __restrict__ tbuf)
{
    int tb = blockIdx.x;
    int l = 0;
    #pragma unroll
    for (int i = 0; i < 5; i++) if (tb >= P.cum[i]) l = i + 1;
    int prev = l ? P.cum[l - 1] : 0;
    int rem = tb - prev;
    const int gx = P.gxs[l];
    const int ty = rem / gx;
    const int tx = rem - ty * gx;
    const int H = P.Hs[l], W = P.Ws[l];
    const long hw = (long)H * W;
    const float* fb = P.feat[l] + (long)blockIdx.z * 256 * hw;
    _Float16* tl = tbuf + P.toff[l] + (long)blockIdx.z * hw * 256;

    __shared__ __align__(16) _Float16 sB[180 * 40];   // [pos][32c + 8 pad]

    const int tid  = threadIdx.x;
    const int lane = tid & 63;
    const int wid  = tid >> 6;
    const int x0   = tx * 16;
    const int ty0  = ty * 8;
    const int oh   = wid >> 1;
    const int ph   = wid & 1;
    const int lr32 = lane & 31;
    const int kg   = lane >> 5;
    const int nrow = lr32 >> 4;
    const int ncol = lane & 15;

    f32x16 acc[4][2] = {};

    for (int c0 = 0; c0 < 256; c0 += 32) {
        __syncthreads();
        // stage: lane loads 8 channels @ one pos, packs fp16, one b128 write
        for (int e = tid; e < 720; e += 256) {
            int qg  = e / 180;            // channel octet 0..3
            int pos = e - qg * 180;
            int r   = pos / 18;
            int col = pos - r * 18;
            int gr = ty0 + r - 1;
            int gc = x0 + col - 1;
            half8 v = {};
            if (gr >= 0 && gr < H && gc >= 0 && gc < W) {
                const float* p = fb + (long)(c0 + qg * 8) * hw + (long)gr * W + gc;
                #pragma unroll
                for (int i = 0; i < 8; i++) { v[i] = (_Float16)(*p); p += hw; }
            }
            *(half8*)(sB + pos * 40 + qg * 8) = v;
        }
        __syncthreads();

        #pragma unroll
        for (int tap = 0; tap < 9; tap++) {
            const int dy = tap / 3;
            const int dx = tap - dy * 3;
            #pragma unroll
            for (int ks = 0; ks < 2; ks++) {
                const int cgt = (c0 >> 3) + ks * 2 + kg;
                const long ao = ((long)(tap * 32 + cgt) * 256 + oh * 128 + lr32) * 8;
                half8 Ah[4], Al[4];
                #pragma unroll
                for (int of = 0; of < 4; of++) {
                    Ah[of] = *(const half8*)(wh + ao + of * 256);
                    Al[of] = *(const half8*)(wl + ao + of * 256);
                }
                #pragma unroll
                for (int pf = 0; pf < 2; pf++) {
                    const int pos = (ph * 4 + pf * 2 + nrow + dy) * 18 + ncol + dx;
                    half8 Bv = *(const half8*)(sB + pos * 40 + ks * 16 + kg * 8);
                    #pragma unroll
                    for (int of = 0; of < 4; of++) {
                        acc[of][pf] = __builtin_amdgcn_mfma_f32_32x32x16_f16(Ah[of], Bv, acc[of][pf], 0, 0, 0);
                        acc[of][pf] = __builtin_amdgcn_mfma_f32_32x32x16_f16(Al[of], Bv, acc[of][pf], 0, 0, 0);
                    }
                }
            }
        }
    }

    // epilogue: bias+relu, NHWC fp16, packed 4-oc (8 B) stores
    const int x = x0 + ncol;
    if (x < W) {
        #pragma unroll
        for (int pf = 0; pf < 2; pf++) {
            const int row = ty0 + ph * 4 + pf * 2 + nrow;
            if (row < H) {
                long pb = ((long)row * W + x) * 256;
                #pragma unroll
                for (int of = 0; of < 4; of++) {
                    #pragma unroll
                    for (int q = 0; q < 4; q++) {
                        const int ob = oh * 128 + of * 32 + kg * 4 + 8 * q;
                        float4 b4 = *(const float4*)(bias + ob);
                        half4 hv;
                        hv[0] = (_Float16)fmaxf(acc[of][pf][q * 4 + 0] + b4.x, 0.f);
                        hv[1] = (_Float16)fmaxf(acc[of][pf][q * 4 + 1] + b4.y, 0.f);
                        hv[2] = (_Float16)fmaxf(acc[of][pf][q * 4 + 2] + b4.z, 0.f);
                        hv[3] = (_Float16)fmaxf(acc[of][pf][q * 4 + 3] + b4.w, 0.f);
                        *(half4*)(tl + pb + ob) = hv;
                    }
                }
            }
        }
    }
}

// Proj: each wave owns one 64-px tile. MFMA 48x256 x px, LDS bounce, epilogue.
__global__ __launch_bounds__(256, 2) void proj_all_kernel(
    ProjParams P,
    const _Float16* __restrict__ tbuf,
    const _Float16* __restrict__ pAh,
    const _Float16* __restrict__ pAl,
    const float* __restrict__ cls_b,
    const float* __restrict__ off_b,
    float* __restrict__ out)
{
    __shared__ __align__(16) float sOut[4][64 * 52];
    const int tid  = threadIdx.x;
    const int lane = tid & 63;
    const int wid  = tid >> 6;

    int tile = blockIdx.x * 4 + wid;
    const bool tvalid = tile < NTILE;
    if (!tvalid) tile = NTILE - 1;
    int l = 0;
    #pragma unroll
    for (int i = 0; i < 5; i++) if (tile >= P.tcum[i]) l = i + 1;
    const int tprev = l ? P.tcum[l - 1] : 0;
    const long hw = P.hws[l];
    const long npx2 = 2 * hw;
    const long px0 = (long)(tile - tprev) * 64;
    const _Float16* tl = tbuf + P.toff[l];

    const int m16 = lane & 15;
    const int kq  = lane >> 4;

    f32x4 acc[3][4] = {};
    #pragma unroll
    for (int ks = 0; ks < 8; ks++) {
        half8 Ah[3], Al[3];
        #pragma unroll
        for (int mt = 0; mt < 3; mt++) {
            const long ao = (long)((mt * 8 + ks) * 64 + lane) * 8;
            Ah[mt] = *(const half8*)(pAh + ao);
            Al[mt] = *(const half8*)(pAl + ao);
        }
        #pragma unroll
        for (int nf = 0; nf < 4; nf++) {
            long px2 = px0 + nf * 16 + m16;
            if (px2 >= npx2) px2 = npx2 - 1;
            half8 Bv = *(const half8*)(tl + px2 * 256 + ks * 32 + kq * 8);
            #pragma unroll
            for (int mt = 0; mt < 3; mt++) {
                acc[mt][nf] = __builtin_amdgcn_mfma_f32_16x16x32_f16(Ah[mt], Bv, acc[mt][nf], 0, 0, 0);
                acc[mt][nf] = __builtin_amdgcn_mfma_f32_16x16x32_f16(Al[mt], Bv, acc[mt][nf], 0, 0, 0);
            }
        }
    }

    // bounce: [px-in-tile][52] fp32, conflict-free stride
    float* so = sOut[wid];
    #pragma unroll
    for (int nf = 0; nf < 4; nf++)
        #pragma unroll
        for (int mt = 0; mt < 3; mt++)
            *(f32x4*)(so + (nf * 16 + m16) * 52 + mt * 16 + kq * 4) = acc[mt][nf];
    __syncthreads();

    float v[48];
    #pragma unroll
    for (int j = 0; j < 12; j++) {
        f32x4 t4 = *(const f32x4*)(so + lane * 52 + j * 4);
        v[j*4+0] = t4[0]; v[j*4+1] = t4[1]; v[j*4+2] = t4[2]; v[j*4+3] = t4[3];
    }

    long px2 = px0 + lane;
    const bool pvalid = tvalid && (px2 < npx2);
    if (px2 >= npx2) px2 = npx2 - 1;
    const int b = px2 >= hw;
    const long pix = px2 - (b ? hw : 0);

    const float* eb = P.eps[l] + (long)b * 20 * hw + pix;
    const float* gb = P.gum[l] + (long)b * 5 * hw + pix;

    float wlog[5];
    float m = -1e30f;
    #pragma unroll
    for (int k = 0; k < 5; k++) {
        float u = gb[(long)k * hw];
        float g = -logf(-logf(u + 1e-10f) + 1e-10f);
        wlog[k] = (g + v[42 + k] + off_b[40 + k]) * 10.0f;
        m = fmaxf(m, wlog[k]);
    }
    float s = 0.f, cw[5];
    #pragma unroll
    for (int k = 0; k < 5; k++) { cw[k] = expf(wlog[k] - m); s += cw[k]; }
    float inv = 1.0f / s;

    float bbox[4] = {0.f, 0.f, 0.f, 0.f};
    #pragma unroll
    for (int k = 0; k < 5; k++) {
        float cwk = cw[k] * inv;
        #pragma unroll
        for (int j = 0; j < 4; j++) {
            int kj = k * 4 + j;
            float mean = v[2 + kj]  + off_b[kj];
            float lstd = v[22 + kj] + off_b[20 + kj];
            float sv = fmaf(expf(lstd), eb[(long)kj * hw], mean);
            bbox[j] = fmaf(cwk, sv, bbox[j]);
        }
    }

    if (pvalid) {
        float* ob = out + (long)b * TOTAL_PER_B + P.loff[l];
        float2 c2; c2.x = v[0] + cls_b[0]; c2.y = v[1] + cls_b[1];
        *(float2*)(ob + pix * 2) = c2;
        float* o2 = ob + hw * 2 + pix * 4;
        float2 b01; b01.x = bbox[0]; b01.y = bbox[1];
        float2 b23; b23.x = bbox[2]; b23.y = bbox[3];
        *(float2*)o2 = b01;
        *(float2*)(o2 + 2) = b23;
    }
}

extern "C" void kernel_launch(void* const* d_in, const int* in_sizes, int n_in,
                              void* d_out, int out_size, void* d_ws, size_t ws_size,
                              hipStream_t stream)
{
    static const int LH[5] = {200, 100, 50, 25, 13};
    static const int LW[5] = {336, 168, 84, 42, 21};

    const float* conv_w = (const float*)d_in[15];
    const float* conv_b = (const float*)d_in[16];
    const float* cls_w  = (const float*)d_in[17];
    const float* cls_b  = (const float*)d_in[18];
    const float* off_w  = (const float*)d_in[19];
    const float* off_b  = (const float*)d_in[20];

    _Float16* wh  = (_Float16*)d_ws;
    _Float16* wl  = wh + WT_F;
    _Float16* pAh = wl + WT_F;
    _Float16* pAl = pAh + PA_F;
    _Float16* tbuf = pAl + PA_F;

    ConvParams cp;
    ProjParams pp;
    long toff = 0, loff = 0;
    int cum = 0, tcum = 0;
    for (int l = 0; l < 5; l++) {
        int H = LH[l], W = LW[l];
        long hw = (long)H * W;
        cp.feat[l] = (const float*)d_in[3 * l];
        pp.eps[l]  = (const float*)d_in[3 * l + 1];
        pp.gum[l]  = (const float*)d_in[3 * l + 2];
        cp.toff[l] = toff; pp.toff[l] = toff;
        cp.Hs[l] = H; cp.Ws[l] = W;
        pp.hws[l] = hw;
        int gx = (W + 15) / 16, gy = (H + 7) / 8;
        cp.gxs[l] = gx;
        cum += gx * gy;
        cp.cum[l] = cum;
        pp.loff[l] = loff;
        tcum += (int)((2 * hw + 63) / 64);
        pp.tcum[l] = tcum;
        toff += 2L * hw * 256;
        loff += 6L * hw;
    }

    prep_kernel<<<32, 256, 0, stream>>>(conv_w, cls_w, off_w, wh, wl, pAh, pAl);

    conv_all_kernel<<<dim3((unsigned)cum, 1, 2), 256, 0, stream>>>(
        cp, wh, wl, conv_b, tbuf);

    proj_all_kernel<<<dim3((unsigned)((NTILE + 3) / 4)), 256, 0, stream>>>(
        pp, tbuf, pAh, pAl, cls_b, off_b, (float*)d_out);
}